// Round 1
// baseline (1707.424 us; speedup 1.0000x reference)
//
#include <hip/hip_runtime.h>
#include <math.h>

#define H 128
#define NLAYER 2
#define EDG 400000
#define NATOM 600000
#define NREL 13
#define SEGS 14
#define RDX 256
#define TILE 4096

typedef unsigned short u16;
typedef unsigned int u32;
using short8  = __attribute__((ext_vector_type(8))) short;
using ushort8 = __attribute__((ext_vector_type(8))) unsigned short;
using floatx4 = __attribute__((ext_vector_type(4))) float;

static constexpr int NODE_N[3]   = {20000, 20000, 10000};
static constexpr int TYPE_OFF[3] = {0, 20000, 40000};
static constexpr int SRC_T[NREL] = {0,0,0,0,0,2,1,2,2,1,1,1,1};
static constexpr int DST_T[NREL] = {2,2,1,1,1,1,1,0,0,0,0,0,2};

// relations grouped by dst type (for fused GAT)
static constexpr int NREL_OF[3]    = {5, 5, 3};
static constexpr int RELS_OF[3][5] = {{7,8,9,10,11},{2,3,4,5,6},{0,1,12}};
// index of relation r within RELS_OF[DST_T[r]]
static constexpr int RR_LOCAL[NREL] = {0,1,0,1,2,3,4,0,1,2,3,4,2};

// per-relation row offsets into the XLb / XRb projection tables
static constexpr int XOFF_S[NREL] = {0,20000,40000,60000,80000,100000,110000,130000,140000,150000,170000,190000,210000};
static constexpr int XOFF_D[NREL] = {0,10000,20000,40000,60000,80000,100000,120000,140000,160000,180000,200000,220000};
#define XTOT 230000

// segments: 0 = atoms (int2 pairs, key bits [0,15)), 1..13 = edges (u32 packed, key bits [15,30))
static constexpr int SEG_N[SEGS]  = {20000,10000,10000,20000,20000,20000,20000,20000,20000,20000,20000,20000,20000,10000};
static constexpr int SEG_RO[SEGS] = {0,20001,30002,40003,60004,80005,100006,120007,140008,160009,180010,200011,220012,240013};
#define RP_TOTAL 250016

static constexpr int    SLEN[SEGS]   = {600000,EDG,EDG,EDG,EDG,EDG,EDG,EDG,EDG,EDG,EDG,EDG,EDG,EDG};
static constexpr int    RNB[SEGS]    = {147,98,98,98,98,98,98,98,98,98,98,98,98,98};   // ceil(len/TILE)
static constexpr int    RBHOFF[SEGS] = {0,37632,62720,87808,112896,137984,163072,188160,213248,238336,263424,288512,313600,338688};
#define BH_TOTAL 363776

__device__ __forceinline__ float wave_reduce_sum(float v) {
#pragma unroll
  for (int off = 32; off > 0; off >>= 1) v += __shfl_xor(v, off, 64);
  return v;
}

__device__ __forceinline__ u16 f2bf(float f) {
  union { float f; u32 u; } c; c.f = f;
  u32 u = c.u + 0x7fffu + ((c.u >> 16) & 1u);   // RNE
  return (u16)(u >> 16);
}
__device__ __forceinline__ float bf2f(u16 h) { union { u32 i; float f; } c; c.i = (u32)h << 16; return c.f; }
__device__ __forceinline__ float bflo(u32 u) { union { u32 i; float f; } c; c.i = u << 16; return c.f; }
__device__ __forceinline__ float bfhi(u32 u) { union { u32 i; float f; } c; c.i = u & 0xffff0000u; return c.f; }

__device__ __forceinline__ int digof(u32 v, int shift) { return (int)((v >> shift) & 255u); }
__device__ __forceinline__ int digof(int2 v, int shift) { return (v.x >> shift) & 255; }

// ---------------- radix sort (2 passes, stable, no global atomics; templated on element) ----------------

__global__ __launch_bounds__(256) void radix_init_a(const int* __restrict__ hyper, int2* __restrict__ Aa) {
  int i = blockIdx.x * 256 + threadIdx.x;
  if (i >= NATOM) return;
  Aa[i] = make_int2(hyper[i], i);
}

__global__ __launch_bounds__(256) void radix_init_e(const int* __restrict__ ei, u32* __restrict__ Ae) {
  int r = blockIdx.y;
  int i = blockIdx.x * 256 + threadIdx.x;
  if (i >= EDG) return;
  u32 src = (u32)ei[(size_t)(r * 2) * EDG + i];
  u32 dst = (u32)ei[(size_t)(r * 2 + 1) * EDG + i];
  Ae[(size_t)r * EDG + i] = (dst << 15) | src;
}

template <typename T>
__global__ __launch_bounds__(256) void radix_count_t(const T* __restrict__ in,
                                                     int* __restrict__ bh, int shift, int seg0) {
  int s = seg0 + blockIdx.y, bx = blockIdx.x;
  int nb = RNB[s];
  __shared__ int h[RDX];
  int t = threadIdx.x;
  h[t] = 0;
  __syncthreads();
  int len = SLEN[s];
  size_t poff = (s == 0) ? 0 : (size_t)(s - 1) * EDG;
#pragma unroll
  for (int i = 0; i < 16; ++i) {
    int p = bx * TILE + i * 256 + t;
    if (p < len) atomicAdd(&h[digof(in[poff + p], shift)], 1);
  }
  __syncthreads();
  bh[RBHOFF[s] + t * nb + bx] = h[t];
}

__global__ __launch_bounds__(256) void radix_scan(int* __restrict__ bh) {
  int s = blockIdx.x;
  int total = RNB[s] * RDX;
  int off = RBHOFF[s];
  __shared__ int sums[256];
  int t = threadIdx.x;
  int chunk = (total + 255) >> 8;
  int b = t * chunk, e = min(b + chunk, total);
  int acc = 0;
  for (int i = b; i < e; ++i) acc += bh[off + i];
  sums[t] = acc;
  __syncthreads();
  for (int o2 = 1; o2 < 256; o2 <<= 1) {
    int v = (t >= o2) ? sums[t - o2] : 0;
    __syncthreads();
    sums[t] += v;
    __syncthreads();
  }
  int pre = t ? sums[t - 1] : 0;
  for (int i = b; i < e; ++i) { int c = bh[off + i]; bh[off + i] = pre; pre += c; }
}

template <typename T>
__global__ __launch_bounds__(256) void radix_scat_t(const T* __restrict__ in,
                                                    T* __restrict__ out,
                                                    const int* __restrict__ bh, int shift, int seg0) {
  int s = seg0 + blockIdx.y, bx = blockIdx.x;
  int nb = RNB[s];
  __shared__ T stg[TILE];
  __shared__ int wc[4][RDX];
  __shared__ int pw[4][RDX];
  __shared__ int basev[RDX];
  __shared__ int lstart[RDX];
  __shared__ int delta[RDX];
  int t = threadIdx.x;
  int lane = t & 63, w = t >> 6;
  unsigned long long lmask = (1ull << lane) - 1ull;
  int len = SLEN[s];
  size_t poff = (s == 0) ? 0 : (size_t)(s - 1) * EDG;
  T kv[16]; int dg[16]; int rk[16];
  basev[t] = 0;
#pragma unroll
  for (int i = 0; i < 16; ++i) {
    int p = bx * TILE + i * 256 + t;
    kv[i] = (p < len) ? in[poff + p] : T{};
  }
  __syncthreads();
  for (int i = 0; i < 16; ++i) {
    int p = bx * TILE + i * 256 + t;
    bool valid = p < len;
    int d = digof(kv[i], shift);
    wc[0][t] = 0; wc[1][t] = 0; wc[2][t] = 0; wc[3][t] = 0;
    __syncthreads();
    unsigned long long m = __ballot(valid);
#pragma unroll
    for (int b2 = 0; b2 < 8; ++b2) {
      unsigned long long bal = __ballot((d >> b2) & 1);
      m &= ((d >> b2) & 1) ? bal : ~bal;
    }
    int riw = __popcll(m & lmask);
    if (valid && riw == 0) wc[w][d] = __popcll(m);
    __syncthreads();
    int s0 = 0;
#pragma unroll
    for (int ww = 0; ww < 4; ++ww) { pw[ww][t] = s0; s0 += wc[ww][t]; }
    __syncthreads();
    dg[i] = d;
    rk[i] = basev[d] + pw[w][d] + riw;
    __syncthreads();
    basev[t] += s0;
    __syncthreads();
  }
  int tot = basev[t];
  pw[0][t] = tot;
  __syncthreads();
  for (int o2 = 1; o2 < 256; o2 <<= 1) {
    int v = (t >= o2) ? pw[0][t - o2] : 0;
    __syncthreads();
    pw[0][t] += v;
    __syncthreads();
  }
  int ls = pw[0][t] - tot;
  lstart[t] = ls;
  delta[t] = bh[RBHOFF[s] + t * nb + bx] - ls;
  __syncthreads();
#pragma unroll
  for (int i = 0; i < 16; ++i) {
    int p = bx * TILE + i * 256 + t;
    if (p < len) stg[lstart[dg[i]] + rk[i]] = kv[i];
  }
  __syncthreads();
  int vc = min(len - bx * TILE, TILE);
#pragma unroll
  for (int i = 0; i < 16; ++i) {
    int p = i * 256 + t;
    if (p < vc) {
      T pr = stg[p];
      int d = digof(pr, shift);
      out[poff + delta[d] + p] = pr;
    }
  }
}

__global__ __launch_bounds__(256) void build_rp_a(const int2* __restrict__ Aa, int* __restrict__ rp) {
  int j = blockIdx.x * 256 + threadIdx.x;
  if (j >= NATOM) return;
  int k = Aa[j].x;
  int kprev = (j == 0) ? -1 : Aa[j - 1].x;
  for (int d = kprev + 1; d <= k; ++d) rp[d] = j;
  if (j == NATOM - 1)
    for (int d = k + 1; d <= 20000; ++d) rp[d] = NATOM;
}

__global__ __launch_bounds__(256) void build_rp_e(const u32* __restrict__ Ae, int* __restrict__ rp) {
  int r = blockIdx.y;
  int j = blockIdx.x * 256 + threadIdx.x;
  if (j >= EDG) return;
  const u32* Ar = Ae + (size_t)r * EDG;
  int ro = SEG_RO[r + 1];
  int n = SEG_N[r + 1];
  int k = (int)(Ar[j] >> 15);
  int kprev = (j == 0) ? -1 : (int)(Ar[j - 1] >> 15);
  for (int d = kprev + 1; d <= k; ++d) rp[ro + d] = j;
  if (j == EDG - 1)
    for (int d = k + 1; d <= n; ++d) rp[ro + d] = EDG;
}

// ---------------- merged per-dst edge stream + degree-balanced scheduling ----------------

// per-dst: per-relation prefix (pre) and total degree (deg)
__global__ __launch_bounds__(256) void merged_meta(const int* __restrict__ rp,
                                                   int* __restrict__ pre,
                                                   int* __restrict__ deg) {
  int d = blockIdx.x * 256 + threadIdx.x;
  if (d >= 50000) return;
  int dt = d < 20000 ? 0 : (d < 40000 ? 1 : 2);
  int dl = d - TYPE_OFF[dt];
  int nr = NREL_OF[dt];
  int acc = 0;
  for (int rr = 0; rr < nr; ++rr) {
    int r = RELS_OF[dt][rr];
    const int* rpr = rp + SEG_RO[r + 1];
    pre[XOFF_D[r] + dl] = acc;
    acc += rpr[dl + 1] - rpr[dl];
  }
  deg[d] = acc;
}

// exclusive scan of deg[0..50000) -> rpm[0..50000]
__global__ __launch_bounds__(256) void scan_deg(const int* __restrict__ deg, int* __restrict__ rpm) {
  __shared__ int sums[256];
  int t = threadIdx.x;
  const int chunk = 196;               // 256*196 = 50176 >= 50000
  int b = t * chunk, e = min(b + chunk, 50000);
  int acc = 0;
  for (int i = b; i < e; ++i) acc += deg[i];
  sums[t] = acc;
  __syncthreads();
  for (int o2 = 1; o2 < 256; o2 <<= 1) {
    int v = (t >= o2) ? sums[t - o2] : 0;
    __syncthreads();
    sums[t] += v;
    __syncthreads();
  }
  int pre = t ? sums[t - 1] : 0;
  for (int i = b; i < e; ++i) { rpm[i] = pre; pre += deg[i]; }
  if (t == 255) rpm[50000] = pre;
}

// per-type counting sort of dsts by total degree, DESCENDING (heavy first)
__global__ __launch_bounds__(256) void build_perm(const int* __restrict__ deg, int* __restrict__ perm) {
  int ty = blockIdx.x;
  int tid = threadIdx.x;
  __shared__ int hist[1024];
  __shared__ int ws2[256];
  int n = NODE_N[ty], off = TYPE_OFF[ty];
  for (int i = tid; i < 1024; i += 256) hist[i] = 0;
  __syncthreads();
  for (int i = tid; i < n; i += 256) {
    int k = 1023 - min(deg[off + i], 1023);
    atomicAdd(&hist[k], 1);
  }
  __syncthreads();
  int s0 = 0;
#pragma unroll
  for (int q = 0; q < 4; ++q) s0 += hist[tid * 4 + q];
  ws2[tid] = s0;
  __syncthreads();
  for (int o2 = 1; o2 < 256; o2 <<= 1) {
    int v = (tid >= o2) ? ws2[tid - o2] : 0;
    __syncthreads();
    ws2[tid] += v;
    __syncthreads();
  }
  int pre2 = tid ? ws2[tid - 1] : 0;
  int vals[4];
#pragma unroll
  for (int q = 0; q < 4; ++q) { vals[q] = pre2; pre2 += hist[tid * 4 + q]; }
  __syncthreads();
#pragma unroll
  for (int q = 0; q < 4; ++q) hist[tid * 4 + q] = vals[q];
  __syncthreads();
  for (int i = tid; i < n; i += 256) {
    int k = 1023 - min(deg[off + i], 1023);
    int pos = atomicAdd(&hist[k], 1);
    perm[off + pos] = off + i;         // global dst id
  }
}

// scatter sorted per-rel edges into merged stream: payload = (rr_local<<18) | abs XL row
__global__ __launch_bounds__(256) void merged_scatter(const u32* __restrict__ Ae,
                                                      const int* __restrict__ rp,
                                                      const int* __restrict__ rpm,
                                                      const int* __restrict__ pre,
                                                      u32* __restrict__ Em) {
  int r = blockIdx.y;
  int j = blockIdx.x * 256 + threadIdx.x;
  if (j >= EDG) return;
  u32 p = Ae[(size_t)r * EDG + j];
  int dst = (int)(p >> 15);
  int src = (int)(p & 32767u);
  int dt = DST_T[r];
  int rank = j - rp[SEG_RO[r + 1] + dst];
  int pos = rpm[TYPE_OFF[dt] + dst] + pre[XOFF_D[r] + dst] + rank;
  Em[pos] = ((u32)RR_LOCAL[r] << 18) | (u32)(XOFF_S[r] + src);
}

// cbs[l][t][c] = sum over relations of type t of cb[l][r][c]
__global__ __launch_bounds__(256) void cb_sum(const float* __restrict__ cb, float* __restrict__ cbs) {
  int i = blockIdx.x * 256 + threadIdx.x;
  if (i >= NLAYER * 3 * H) return;
  int c = i & 127, t = (i >> 7) % 3, l = i / (3 * H);
  float s = 0.f;
  for (int rr = 0; rr < NREL_OF[t]; ++rr)
    s += cb[((size_t)l * NREL + RELS_OF[t][rr]) * H + c];
  cbs[i] = s;
}

// ---------------- atom mean aggregation: 2 chems/wave, 32-lane groups, float4 ----------------

__global__ __launch_bounds__(256) void mean_atoms(const float* __restrict__ x_atom,
                                                  const int* __restrict__ rp,
                                                  const int2* __restrict__ pairs,
                                                  float* __restrict__ Mean) {
  int wave = (blockIdx.x * blockDim.x + threadIdx.x) >> 6;
  int lane = threadIdx.x & 63;
  int g = lane >> 5, l32 = lane & 31;
  int chem = wave * 2 + g;
  if (chem >= 20000) return;
  int b = rp[chem], e = rp[chem + 1];
  float4 s = make_float4(0.f, 0.f, 0.f, 0.f);
  for (int j = b; j < e; ++j) {
    int a = pairs[j].y;
    float4 v = *(const float4*)(x_atom + (size_t)a * H + l32 * 4);
    s.x += v.x; s.y += v.y; s.z += v.z; s.w += v.w;
  }
  float inv = 1.0f / fmaxf((float)(e - b), 1.0f);
  float4 o; o.x = s.x * inv; o.y = s.y * inv; o.z = s.z * inv; o.w = s.w * inv;
  *(float4*)(Mean + (size_t)chem * H + l32 * 4) = o;
}

// ---------------- fp32 projection (W_mol): xsb[chem] = bf16(Mean @ W + x_chem) ----------------

__global__ __launch_bounds__(256) void proj_kernel(
    const float* __restrict__ X, const float* __restrict__ W,
    const float* __restrict__ Res, u16* __restrict__ Yb, int N) {
  int r0 = blockIdx.x * 64;
  if (r0 >= N) return;
  __shared__ float Xs[64][132];
  int tid = threadIdx.x;
#pragma unroll
  for (int i = 0; i < 8; ++i) {
    int f = tid + 256 * i;
    int row = f >> 5, c4 = (f & 31) << 2;
    float4 v = make_float4(0.f, 0.f, 0.f, 0.f);
    if (r0 + row < N) v = *(const float4*)(X + (size_t)(r0 + row) * H + c4);
    *(float4*)&Xs[row][c4] = v;
  }
  __syncthreads();
  int trow = tid >> 5, tcol = tid & 31;
  float acc[8][4] = {};
#pragma unroll 4
  for (int k = 0; k < 128; ++k) {
    float4 w = *(const float4*)(W + k * H + tcol * 4);
#pragma unroll
    for (int i = 0; i < 8; ++i) {
      float xv = Xs[trow * 8 + i][k];
      acc[i][0] = fmaf(xv, w.x, acc[i][0]);
      acc[i][1] = fmaf(xv, w.y, acc[i][1]);
      acc[i][2] = fmaf(xv, w.z, acc[i][2]);
      acc[i][3] = fmaf(xv, w.w, acc[i][3]);
    }
  }
#pragma unroll
  for (int i = 0; i < 8; ++i) {
    int row = r0 + trow * 8 + i;
    if (row < N) {
      float4 rv = *(const float4*)(Res + (size_t)row * H + tcol * 4);
      u32 lo = (u32)f2bf(acc[i][0] + rv.x) | ((u32)f2bf(acc[i][1] + rv.y) << 16);
      u32 hi = (u32)f2bf(acc[i][2] + rv.z) | ((u32)f2bf(acc[i][3] + rv.w) << 16);
      *(uint2*)(Yb + (size_t)row * H + tcol * 4) = make_uint2(lo, hi);
    }
  }
}

// ---------------- converts ----------------

// xsb rows [20000,50000) = bf16([x_gene | x_assay])
__global__ __launch_bounds__(256) void conv_xs(const float* __restrict__ x_gene,
                                               const float* __restrict__ x_assay,
                                               u16* __restrict__ xsb) {
  int idx = 20000 * H + (blockIdx.x * 256 + threadIdx.x) * 4;
  if (idx >= 50000 * H) return;
  int row = idx >> 7;
  const float* src = (row < 40000) ? x_gene + (idx - 20000 * H) : x_assay + (idx - 40000 * H);
  float4 v = *(const float4*)src;
  u32 p0 = (u32)f2bf(v.x) | ((u32)f2bf(v.y) << 16);
  u32 p1 = (u32)f2bf(v.z) | ((u32)f2bf(v.w) << 16);
  u32* o = (u32*)(xsb + idx);
  o[0] = p0; o[1] = p1;
}

// WB[(mat*2+side)][n][k] = bf16( (side?Wr:Wl)[mat][k][n] )
__global__ __launch_bounds__(256) void conv_weights(const float* __restrict__ Wl,
                                                    const float* __restrict__ Wr,
                                                    u16* __restrict__ WB) {
  int mat = blockIdx.x;
  int side = blockIdx.y;
  const float* W = (side ? Wr : Wl) + (size_t)mat * H * H;
  u16* O = WB + ((size_t)mat * 2 + side) * H * H;
  for (int f = threadIdx.x; f < H * H; f += 256) {
    int n = f >> 7, k = f & 127;
    O[f] = f2bf(W[k * H + n]);
  }
}

// ---------------- batched bf16 MFMA projection: all 26 GEMMs of one layer ----------------

__global__ __launch_bounds__(256) void proj_mfma(
    const u16* __restrict__ xsb, const u16* __restrict__ WB,
    const float* __restrict__ bl, const float* __restrict__ br,
    u16* __restrict__ XLb, u16* __restrict__ XRb, int layer) {
  int by = blockIdx.y;
  int r = by >> 1, side = by & 1;
  int typ = side ? DST_T[r] : SRC_T[r];
  int N = NODE_N[typ];
  int r0 = blockIdx.x * 64;
  if (r0 >= N) return;
  const u16* X = xsb + (size_t)TYPE_OFF[typ] * H;
  const u16* W = WB + ((size_t)(layer * NREL + r) * 2 + side) * H * H;
  const float* bias = (side ? br : bl) + (size_t)(layer * NREL + r) * H;
  u16* Y = side ? (XRb + (size_t)XOFF_D[r] * H) : (XLb + (size_t)XOFF_S[r] * H);

  __shared__ u16 Xs[64 * 136];
  __shared__ u16 Ws[128 * 136];
  int tid = threadIdx.x;
#pragma unroll
  for (int i = 0; i < 4; ++i) {
    int f = tid + 256 * i;
    int row = f >> 4, seg = f & 15;
    ushort8 v = {};
    if (r0 + row < N) v = *(const ushort8*)(X + (size_t)(r0 + row) * H + seg * 8);
    *(ushort8*)(Xs + row * 136 + seg * 8) = v;
  }
#pragma unroll
  for (int i = 0; i < 8; ++i) {
    int f = tid + 256 * i;
    int row = f >> 4, seg = f & 15;
    *(ushort8*)(Ws + row * 136 + seg * 8) = *(const ushort8*)(W + row * H + seg * 8);
  }
  __syncthreads();

  int w = tid >> 6, lane = tid & 63;
  int g = lane >> 4, l16 = lane & 15;
  floatx4 acc[4][2] = {};
#pragma unroll
  for (int kt = 0; kt < 4; ++kt) {
    int k0 = kt * 32 + g * 8;
    short8 a[4], b[2];
#pragma unroll
    for (int rt = 0; rt < 4; ++rt) a[rt] = *(const short8*)(Xs + (rt * 16 + l16) * 136 + k0);
#pragma unroll
    for (int ct = 0; ct < 2; ++ct) b[ct] = *(const short8*)(Ws + (w * 32 + ct * 16 + l16) * 136 + k0);
#pragma unroll
    for (int rt = 0; rt < 4; ++rt)
#pragma unroll
      for (int ct = 0; ct < 2; ++ct)
        acc[rt][ct] = __builtin_amdgcn_mfma_f32_16x16x32_bf16(a[rt], b[ct], acc[rt][ct], 0, 0, 0);
  }
  __syncthreads();
  float bv0 = bias[w * 32 + l16];
  float bv1 = bias[w * 32 + 16 + l16];
#pragma unroll
  for (int rt = 0; rt < 4; ++rt)
#pragma unroll
    for (int ct = 0; ct < 2; ++ct) {
      float bv = ct ? bv1 : bv0;
      int col = w * 32 + ct * 16 + l16;
#pragma unroll
      for (int reg = 0; reg < 4; ++reg) {
        int row = rt * 16 + g * 4 + reg;
        Xs[row * 136 + col] = f2bf(acc[rt][ct][reg] + bv);
      }
    }
  __syncthreads();
#pragma unroll
  for (int i = 0; i < 4; ++i) {
    int f = tid + 256 * i;
    int row = f >> 4, seg = f & 15;
    if (r0 + row < N)
      *(ushort8*)(Y + (size_t)(r0 + row) * H + seg * 8) = *(const ushort8*)(Xs + row * 136 + seg * 8);
  }
}

// ---------------- fused GATv2: merged tagged edge stream, degree-sorted dsts, 4/wave ----------------

__global__ __launch_bounds__(256) void gat_fused(
    const u16* __restrict__ XLb, const u16* __restrict__ XRb,
    const int* __restrict__ rpm, const u32* __restrict__ Em,
    const float* __restrict__ att_a, const float* __restrict__ cbs,
    const int* __restrict__ perm, float* __restrict__ agg, int layer) {
  int wave = (blockIdx.x * blockDim.x + threadIdx.x) >> 6;
  int lane = threadIdx.x & 63;
  int g = lane >> 4, l16 = lane & 15;
  int idx = wave * 4 + g;                  // [0,50000) exactly
  if (idx >= 50000) return;
  int dt = idx < 20000 ? 0 : (idx < 40000 ? 1 : 2);
  int d = perm[idx];                       // actual dst (same type as idx range)
  int dl = d - TYPE_OFF[dt];
  int b = rpm[d], e = rpm[d + 1];
  float o[8] = {};
  float V[8] = {}, xr[8] = {}, av[8] = {};
  float m = -1e30f, s = 0.f;
  int cur = -1;
  int j = b;
  while (j < e) {
    u32 p0 = Em[j];
    int rr0 = (int)(p0 >> 18);
    if (rr0 != cur) {                      // relation switch (rare): fold + reload
      if (cur >= 0) {
        float inv = 1.0f / s;
#pragma unroll
        for (int c = 0; c < 8; ++c) o[c] = fmaf(V[c], inv, o[c]);
      }
      m = -1e30f; s = 0.f;
#pragma unroll
      for (int c = 0; c < 8; ++c) V[c] = 0.f;
      cur = rr0;
      int r = RELS_OF[dt][rr0];
      size_t wi = (size_t)layer * NREL + r;
      ushort8 uxr = *(const ushort8*)(XRb + ((size_t)(XOFF_D[r] + dl) << 7) + (l16 << 3));
      float4 a0 = *(const float4*)(att_a + wi * H + (l16 << 3));
      float4 a1 = *(const float4*)(att_a + wi * H + (l16 << 3) + 4);
      av[0] = a0.x; av[1] = a0.y; av[2] = a0.z; av[3] = a0.w;
      av[4] = a1.x; av[5] = a1.y; av[6] = a1.z; av[7] = a1.w;
#pragma unroll
      for (int c = 0; c < 8; ++c) xr[c] = bf2f((u16)uxr[c]);
    }
    bool two = false;
    u32 p1 = 0;
    if (j + 1 < e) { p1 = Em[j + 1]; two = ((int)(p1 >> 18) == cur); }
    if (two) {                             // fast path: 2 same-relation edges
      int row0 = (int)(p0 & 0x3ffffu), row1 = (int)(p1 & 0x3ffffu);
      ushort8 u0 = *(const ushort8*)(XLb + ((size_t)row0 << 7) + (l16 << 3));
      ushort8 u1 = *(const ushort8*)(XLb + ((size_t)row1 << 7) + (l16 << 3));
      float xl0[8], xl1[8];
      float t0 = 0.f, t1 = 0.f;
#pragma unroll
      for (int c = 0; c < 8; ++c) {
        xl0[c] = bf2f((u16)u0[c]);
        xl1[c] = bf2f((u16)u1[c]);
        float v0 = xl0[c] + xr[c], v1 = xl1[c] + xr[c];
        t0 = fmaf(av[c], fmaxf(v0, 0.2f * v0), t0);
        t1 = fmaf(av[c], fmaxf(v1, 0.2f * v1), t1);
      }
      t0 += __shfl_xor(t0, 1, 64); t1 += __shfl_xor(t1, 1, 64);
      t0 += __shfl_xor(t0, 2, 64); t1 += __shfl_xor(t1, 2, 64);
      t0 += __shfl_xor(t0, 4, 64); t1 += __shfl_xor(t1, 4, 64);
      t0 += __shfl_xor(t0, 8, 64); t1 += __shfl_xor(t1, 8, 64);
      float nm = fmaxf(m, fmaxf(t0, t1));
      float sc = __expf(m - nm);
      float w0 = __expf(t0 - nm), w1 = __expf(t1 - nm);
      s = fmaf(s, sc, w0 + w1);
#pragma unroll
      for (int c = 0; c < 8; ++c)
        V[c] = fmaf(V[c], sc, fmaf(w0, xl0[c], w1 * xl1[c]));
      m = nm;
      j += 2;
    } else {                               // segment tail / boundary: 1 edge
      int row0 = (int)(p0 & 0x3ffffu);
      ushort8 u0 = *(const ushort8*)(XLb + ((size_t)row0 << 7) + (l16 << 3));
      float xl0[8];
      float t0 = 0.f;
#pragma unroll
      for (int c = 0; c < 8; ++c) {
        xl0[c] = bf2f((u16)u0[c]);
        float v0 = xl0[c] + xr[c];
        t0 = fmaf(av[c], fmaxf(v0, 0.2f * v0), t0);
      }
      t0 += __shfl_xor(t0, 1, 64);
      t0 += __shfl_xor(t0, 2, 64);
      t0 += __shfl_xor(t0, 4, 64);
      t0 += __shfl_xor(t0, 8, 64);
      float nm = fmaxf(m, t0);
      float sc = __expf(m - nm);
      float w0 = __expf(t0 - nm);
      s = fmaf(s, sc, w0);
#pragma unroll
      for (int c = 0; c < 8; ++c) V[c] = fmaf(V[c], sc, w0 * xl0[c]);
      m = nm;
      ++j;
    }
  }
  if (cur >= 0) {                          // final fold
    float inv = 1.0f / s;
#pragma unroll
    for (int c = 0; c < 8; ++c) o[c] = fmaf(V[c], inv, o[c]);
  }
  const float* cp = cbs + ((size_t)layer * 3 + dt) * H + (l16 << 3);
  float4 c0 = *(const float4*)cp;
  float4 c1 = *(const float4*)(cp + 4);
  o[0] += c0.x; o[1] += c0.y; o[2] += c0.z; o[3] += c0.w;
  o[4] += c1.x; o[5] += c1.y; o[6] += c1.z; o[7] += c1.w;
  float* ap = agg + (size_t)d * H + (l16 << 3);
  *(float4*)ap       = make_float4(o[0], o[1], o[2], o[3]);
  *(float4*)(ap + 4) = make_float4(o[4], o[5], o[6], o[7]);
}

// ---------------- LayerNorm + ReLU (fp32 in, bf16 out) ----------------

__global__ __launch_bounds__(256) void ln_relu_kernel(const float* __restrict__ agg,
                                                      const float* __restrict__ g,
                                                      const float* __restrict__ b,
                                                      u16* __restrict__ xsb) {
  int row = (blockIdx.x * blockDim.x + threadIdx.x) >> 6;
  int lane = threadIdx.x & 63;
  if (row >= 50000) return;
  int t = row < 20000 ? 0 : (row < 40000 ? 1 : 2);
  float2 x = *(const float2*)(agg + (size_t)row * H + 2 * lane);
  float mu = wave_reduce_sum(x.x + x.y) * (1.f / 128.f);
  float d0 = x.x - mu, d1 = x.y - mu;
  float var = wave_reduce_sum(d0 * d0 + d1 * d1) * (1.f / 128.f);
  float inv = 1.0f / sqrtf(var + 1e-5f);
  float2 gg = *(const float2*)(g + t * H + 2 * lane);
  float2 bb = *(const float2*)(b + t * H + 2 * lane);
  float o0 = fmaxf(d0 * inv * gg.x + bb.x, 0.f);
  float o1 = fmaxf(d1 * inv * gg.y + bb.y, 0.f);
  u32 pk = (u32)f2bf(o0) | ((u32)f2bf(o1) << 16);
  *(u32*)(xsb + (size_t)row * H + 2 * lane) = pk;
}

// ---------------- prediction head ----------------

__global__ __launch_bounds__(256) void pred_kernel(const u16* __restrict__ xsb,
                                                   const float* __restrict__ Wp,
                                                   const float* __restrict__ bp,
                                                   float* __restrict__ out) {
  int row = (blockIdx.x * blockDim.x + threadIdx.x) >> 6;
  int lane = threadIdx.x & 63;
  if (row >= 20000) return;
  u32 u = *(const u32*)(xsb + (size_t)row * H + 2 * lane);
  float x0 = bflo(u), x1 = bfhi(u);
  float4 w = *(const float4*)(Wp + 4 * lane);
  float pA = x0 * w.x + x1 * w.z;
  float pB = x0 * w.y + x1 * w.w;
  pA = wave_reduce_sum(pA);
  pB = wave_reduce_sum(pB);
  if (lane == 0) {
    out[(size_t)row * 2 + 0] = pA + bp[0];
    out[(size_t)row * 2 + 1] = pB + bp[1];
  }
}

// ---------------- launch ----------------

extern "C" void kernel_launch(void* const* d_in, const int* in_sizes, int n_in,
                              void* d_out, int out_size, void* d_ws, size_t ws_size,
                              hipStream_t stream) {
  (void)in_sizes; (void)n_in; (void)out_size; (void)ws_size;
  const float* x_atom  = (const float*)d_in[0];
  const float* x_chem  = (const float*)d_in[1];
  const float* x_gene  = (const float*)d_in[2];
  const float* x_assay = (const float*)d_in[3];
  const float* W_mol   = (const float*)d_in[4];
  const float* Wl      = (const float*)d_in[5];
  const float* Wr      = (const float*)d_in[6];
  const float* bl      = (const float*)d_in[7];
  const float* br      = (const float*)d_in[8];
  const float* att_a   = (const float*)d_in[9];
  const float* cb      = (const float*)d_in[10];
  const float* ln_g    = (const float*)d_in[11];
  const float* ln_b    = (const float*)d_in[12];
  const float* Wp      = (const float*)d_in[13];
  const float* bp      = (const float*)d_in[14];
  const int*   hyper   = (const int*)d_in[15];
  const int*   ei      = (const int*)d_in[16];
  float* out = (float*)d_out;

  float* ws = (float*)d_ws;
  size_t o = 0;
  float* agg  = ws + o; o += (size_t)50000 * H;
  float* Mean = ws + o; o += (size_t)20000 * H;
  int2*  Aa   = (int2*)(ws + o); o += (size_t)2 * NATOM;
  int2*  Ba   = (int2*)(ws + o); o += (size_t)2 * NATOM;
  u32*   Ae   = (u32*)(ws + o); o += (size_t)NREL * EDG;
  u32*   Be   = (u32*)(ws + o); o += (size_t)NREL * EDG;
  int*   rp   = (int*)(ws + o); o += RP_TOTAL;
  int*   bh   = (int*)(ws + o); o += BH_TOTAL;
  u16*   xsb  = (u16*)(ws + o); o += (size_t)50000 * H / 2;
  u16*   WB   = (u16*)(ws + o); o += (size_t)52 * H * H / 2;
  u16*   XLb  = (u16*)(ws + o); o += (size_t)XTOT * H / 2;
  u16*   XRb  = (u16*)(ws + o); o += (size_t)XTOT * H / 2;
  int*   rpm  = (int*)(ws + o); o += 50004;            // padded for alignment
  int*   pre  = (int*)(ws + o); o += 230000;
  int*   deg  = (int*)(ws + o); o += 50000;
  int*   perm = (int*)(ws + o); o += 50000;
  float* cbs  = ws + o; o += (size_t)NLAYER * 3 * H;
  u32*   Em   = Be;  // reuse radix ping-pong scratch (exactly NREL*EDG u32)

  dim3 b256(256);

  // ---- CSR build: atoms (int2) + edges (packed u32), 2-pass stable radix ----
  radix_init_a<<<dim3(2344), b256, 0, stream>>>(hyper, Aa);
  radix_init_e<<<dim3(1563, 13), b256, 0, stream>>>(ei, Ae);
  radix_count_t<int2><<<dim3(147, 1), b256, 0, stream>>>(Aa, bh, 0, 0);
  radix_count_t<u32><<<dim3(98, 13), b256, 0, stream>>>(Ae, bh, 15, 1);
  radix_scan<<<SEGS, b256, 0, stream>>>(bh);
  radix_scat_t<int2><<<dim3(147, 1), b256, 0, stream>>>(Aa, Ba, bh, 0, 0);
  radix_scat_t<u32><<<dim3(98, 13), b256, 0, stream>>>(Ae, Be, bh, 15, 1);
  radix_count_t<int2><<<dim3(147, 1), b256, 0, stream>>>(Ba, bh, 8, 0);
  radix_count_t<u32><<<dim3(98, 13), b256, 0, stream>>>(Be, bh, 23, 1);
  radix_scan<<<SEGS, b256, 0, stream>>>(bh);
  radix_scat_t<int2><<<dim3(147, 1), b256, 0, stream>>>(Ba, Aa, bh, 8, 0);
  radix_scat_t<u32><<<dim3(98, 13), b256, 0, stream>>>(Be, Ae, bh, 23, 1);
  build_rp_a<<<dim3(2344), b256, 0, stream>>>(Aa, rp);
  build_rp_e<<<dim3(1563, 13), b256, 0, stream>>>(Ae, rp);

  // ---- merged tagged edge stream + degree-balanced dst schedule (layer-independent) ----
  merged_meta<<<dim3(196), b256, 0, stream>>>(rp, pre, deg);
  scan_deg<<<dim3(1), b256, 0, stream>>>(deg, rpm);
  build_perm<<<dim3(3), b256, 0, stream>>>(deg, perm);
  merged_scatter<<<dim3(1563, 13), b256, 0, stream>>>(Ae, rp, rpm, pre, Em);
  cb_sum<<<dim3(3), b256, 0, stream>>>(cb, cbs);

  // ---- features: xsb[chem] = bf16(mean @ W_mol + x_chem); xsb[gene|assay] = bf16(raw) ----
  mean_atoms<<<dim3(20000 / 8), b256, 0, stream>>>(x_atom, rp, Aa, Mean);
  proj_kernel<<<dim3(313), b256, 0, stream>>>(Mean, W_mol, x_chem, xsb, 20000);
  conv_xs<<<dim3(3750), b256, 0, stream>>>(x_gene, x_assay, xsb);
  conv_weights<<<dim3(26, 2), b256, 0, stream>>>(Wl, Wr, WB);

  for (int l = 0; l < NLAYER; ++l) {
    proj_mfma<<<dim3(313, 26), b256, 0, stream>>>(xsb, WB, bl, br, XLb, XRb, l);
    gat_fused<<<dim3(3125), b256, 0, stream>>>(XLb, XRb, rpm, Em, att_a, cbs, perm, agg, l);
    ln_relu_kernel<<<dim3(50000 / 4), b256, 0, stream>>>(agg, ln_g + l * 3 * H, ln_b + l * 3 * H, xsb);
  }
  pred_kernel<<<dim3(20000 / 4), b256, 0, stream>>>(xsb, Wp, bp, out);
}

// Round 2
// 1659.961 us; speedup vs baseline: 1.0286x; 1.0286x over previous
//
#include <hip/hip_runtime.h>
#include <math.h>

#define H 128
#define NLAYER 2
#define EDG 400000
#define NATOM 600000
#define NREL 13
#define SEGS 14
#define RDX 256
#define TILE 4096

typedef unsigned short u16;
typedef unsigned int u32;
using short8  = __attribute__((ext_vector_type(8))) short;
using ushort8 = __attribute__((ext_vector_type(8))) unsigned short;
using floatx4 = __attribute__((ext_vector_type(4))) float;

static constexpr int NODE_N[3]   = {20000, 20000, 10000};
static constexpr int TYPE_OFF[3] = {0, 20000, 40000};
static constexpr int SRC_T[NREL] = {0,0,0,0,0,2,1,2,2,1,1,1,1};
static constexpr int DST_T[NREL] = {2,2,1,1,1,1,1,0,0,0,0,0,2};

// relations grouped by dst type (for fused GAT)
static constexpr int NREL_OF[3]    = {5, 5, 3};
static constexpr int RELS_OF[3][5] = {{7,8,9,10,11},{2,3,4,5,6},{0,1,12}};

// per-relation row offsets into the XLb / XRb projection tables
static constexpr int XOFF_S[NREL] = {0,20000,40000,60000,80000,100000,110000,130000,140000,150000,170000,190000,210000};
static constexpr int XOFF_D[NREL] = {0,10000,20000,40000,60000,80000,100000,120000,140000,160000,180000,200000,220000};
#define XTOT 230000

// segments: 0 = atoms (int2 pairs, key bits [0,15)), 1..13 = edges (u32 packed, key bits [15,30))
static constexpr int SEG_N[SEGS]  = {20000,10000,10000,20000,20000,20000,20000,20000,20000,20000,20000,20000,20000,10000};
static constexpr int SEG_RO[SEGS] = {0,20001,30002,40003,60004,80005,100006,120007,140008,160009,180010,200011,220012,240013};
#define RP_TOTAL 250016

static constexpr int    SLEN[SEGS]   = {600000,EDG,EDG,EDG,EDG,EDG,EDG,EDG,EDG,EDG,EDG,EDG,EDG,EDG};
static constexpr int    RNB[SEGS]    = {147,98,98,98,98,98,98,98,98,98,98,98,98,98};   // ceil(len/TILE)
static constexpr int    RBHOFF[SEGS] = {0,37632,62720,87808,112896,137984,163072,188160,213248,238336,263424,288512,313600,338688};
#define BH_TOTAL 363776

__device__ __forceinline__ float wave_reduce_sum(float v) {
#pragma unroll
  for (int off = 32; off > 0; off >>= 1) v += __shfl_xor(v, off, 64);
  return v;
}

__device__ __forceinline__ u16 f2bf(float f) {
  union { float f; u32 u; } c; c.f = f;
  u32 u = c.u + 0x7fffu + ((c.u >> 16) & 1u);   // RNE
  return (u16)(u >> 16);
}
__device__ __forceinline__ float bf2f(u16 h) { union { u32 i; float f; } c; c.i = (u32)h << 16; return c.f; }
__device__ __forceinline__ float bflo(u32 u) { union { u32 i; float f; } c; c.i = u << 16; return c.f; }
__device__ __forceinline__ float bfhi(u32 u) { union { u32 i; float f; } c; c.i = u & 0xffff0000u; return c.f; }

__device__ __forceinline__ int digof(u32 v, int shift) { return (int)((v >> shift) & 255u); }
__device__ __forceinline__ int digof(int2 v, int shift) { return (v.x >> shift) & 255; }

// ---------------- radix sort (2 passes, stable, no global atomics; templated on element) ----------------

__global__ __launch_bounds__(256) void radix_init_a(const int* __restrict__ hyper, int2* __restrict__ Aa) {
  int i = blockIdx.x * 256 + threadIdx.x;
  if (i >= NATOM) return;
  Aa[i] = make_int2(hyper[i], i);
}

__global__ __launch_bounds__(256) void radix_init_e(const int* __restrict__ ei, u32* __restrict__ Ae) {
  int r = blockIdx.y;
  int i = blockIdx.x * 256 + threadIdx.x;
  if (i >= EDG) return;
  u32 src = (u32)ei[(size_t)(r * 2) * EDG + i];
  u32 dst = (u32)ei[(size_t)(r * 2 + 1) * EDG + i];
  Ae[(size_t)r * EDG + i] = (dst << 15) | src;
}

template <typename T>
__global__ __launch_bounds__(256) void radix_count_t(const T* __restrict__ in,
                                                     int* __restrict__ bh, int shift, int seg0) {
  int s = seg0 + blockIdx.y, bx = blockIdx.x;
  int nb = RNB[s];
  __shared__ int h[RDX];
  int t = threadIdx.x;
  h[t] = 0;
  __syncthreads();
  int len = SLEN[s];
  size_t poff = (s == 0) ? 0 : (size_t)(s - 1) * EDG;
#pragma unroll
  for (int i = 0; i < 16; ++i) {
    int p = bx * TILE + i * 256 + t;
    if (p < len) atomicAdd(&h[digof(in[poff + p], shift)], 1);
  }
  __syncthreads();
  bh[RBHOFF[s] + t * nb + bx] = h[t];
}

__global__ __launch_bounds__(256) void radix_scan(int* __restrict__ bh) {
  int s = blockIdx.x;
  int total = RNB[s] * RDX;
  int off = RBHOFF[s];
  __shared__ int sums[256];
  int t = threadIdx.x;
  int chunk = (total + 255) >> 8;
  int b = t * chunk, e = min(b + chunk, total);
  int acc = 0;
  for (int i = b; i < e; ++i) acc += bh[off + i];
  sums[t] = acc;
  __syncthreads();
  for (int o2 = 1; o2 < 256; o2 <<= 1) {
    int v = (t >= o2) ? sums[t - o2] : 0;
    __syncthreads();
    sums[t] += v;
    __syncthreads();
  }
  int pre = t ? sums[t - 1] : 0;
  for (int i = b; i < e; ++i) { int c = bh[off + i]; bh[off + i] = pre; pre += c; }
}

template <typename T>
__global__ __launch_bounds__(256) void radix_scat_t(const T* __restrict__ in,
                                                    T* __restrict__ out,
                                                    const int* __restrict__ bh, int shift, int seg0) {
  int s = seg0 + blockIdx.y, bx = blockIdx.x;
  int nb = RNB[s];
  __shared__ T stg[TILE];
  __shared__ int wc[4][RDX];
  __shared__ int pw[4][RDX];
  __shared__ int basev[RDX];
  __shared__ int lstart[RDX];
  __shared__ int delta[RDX];
  int t = threadIdx.x;
  int lane = t & 63, w = t >> 6;
  unsigned long long lmask = (1ull << lane) - 1ull;
  int len = SLEN[s];
  size_t poff = (s == 0) ? 0 : (size_t)(s - 1) * EDG;
  T kv[16]; int dg[16]; int rk[16];
  basev[t] = 0;
#pragma unroll
  for (int i = 0; i < 16; ++i) {
    int p = bx * TILE + i * 256 + t;
    kv[i] = (p < len) ? in[poff + p] : T{};
  }
  __syncthreads();
  for (int i = 0; i < 16; ++i) {
    int p = bx * TILE + i * 256 + t;
    bool valid = p < len;
    int d = digof(kv[i], shift);
    wc[0][t] = 0; wc[1][t] = 0; wc[2][t] = 0; wc[3][t] = 0;
    __syncthreads();
    unsigned long long m = __ballot(valid);
#pragma unroll
    for (int b2 = 0; b2 < 8; ++b2) {
      unsigned long long bal = __ballot((d >> b2) & 1);
      m &= ((d >> b2) & 1) ? bal : ~bal;
    }
    int riw = __popcll(m & lmask);
    if (valid && riw == 0) wc[w][d] = __popcll(m);
    __syncthreads();
    int s0 = 0;
#pragma unroll
    for (int ww = 0; ww < 4; ++ww) { pw[ww][t] = s0; s0 += wc[ww][t]; }
    __syncthreads();
    dg[i] = d;
    rk[i] = basev[d] + pw[w][d] + riw;
    __syncthreads();
    basev[t] += s0;
    __syncthreads();
  }
  int tot = basev[t];
  pw[0][t] = tot;
  __syncthreads();
  for (int o2 = 1; o2 < 256; o2 <<= 1) {
    int v = (t >= o2) ? pw[0][t - o2] : 0;
    __syncthreads();
    pw[0][t] += v;
    __syncthreads();
  }
  int ls = pw[0][t] - tot;
  lstart[t] = ls;
  delta[t] = bh[RBHOFF[s] + t * nb + bx] - ls;
  __syncthreads();
#pragma unroll
  for (int i = 0; i < 16; ++i) {
    int p = bx * TILE + i * 256 + t;
    if (p < len) stg[lstart[dg[i]] + rk[i]] = kv[i];
  }
  __syncthreads();
  int vc = min(len - bx * TILE, TILE);
#pragma unroll
  for (int i = 0; i < 16; ++i) {
    int p = i * 256 + t;
    if (p < vc) {
      T pr = stg[p];
      int d = digof(pr, shift);
      out[poff + delta[d] + p] = pr;
    }
  }
}

__global__ __launch_bounds__(256) void build_rp_a(const int2* __restrict__ Aa, int* __restrict__ rp) {
  int j = blockIdx.x * 256 + threadIdx.x;
  if (j >= NATOM) return;
  int k = Aa[j].x;
  int kprev = (j == 0) ? -1 : Aa[j - 1].x;
  for (int d = kprev + 1; d <= k; ++d) rp[d] = j;
  if (j == NATOM - 1)
    for (int d = k + 1; d <= 20000; ++d) rp[d] = NATOM;
}

__global__ __launch_bounds__(256) void build_rp_e(const u32* __restrict__ Ae, int* __restrict__ rp) {
  int r = blockIdx.y;
  int j = blockIdx.x * 256 + threadIdx.x;
  if (j >= EDG) return;
  const u32* Ar = Ae + (size_t)r * EDG;
  int ro = SEG_RO[r + 1];
  int n = SEG_N[r + 1];
  int k = (int)(Ar[j] >> 15);
  int kprev = (j == 0) ? -1 : (int)(Ar[j - 1] >> 15);
  for (int d = kprev + 1; d <= k; ++d) rp[ro + d] = j;
  if (j == EDG - 1)
    for (int d = k + 1; d <= n; ++d) rp[ro + d] = EDG;
}

// ---------------- atom mean aggregation: 2 chems/wave, 32-lane groups, float4 ----------------

__global__ __launch_bounds__(256) void mean_atoms(const float* __restrict__ x_atom,
                                                  const int* __restrict__ rp,
                                                  const int2* __restrict__ pairs,
                                                  float* __restrict__ Mean) {
  int wave = (blockIdx.x * blockDim.x + threadIdx.x) >> 6;
  int lane = threadIdx.x & 63;
  int g = lane >> 5, l32 = lane & 31;
  int chem = wave * 2 + g;
  if (chem >= 20000) return;
  int b = rp[chem], e = rp[chem + 1];
  float4 s = make_float4(0.f, 0.f, 0.f, 0.f);
  for (int j = b; j < e; ++j) {
    int a = pairs[j].y;
    float4 v = *(const float4*)(x_atom + (size_t)a * H + l32 * 4);
    s.x += v.x; s.y += v.y; s.z += v.z; s.w += v.w;
  }
  float inv = 1.0f / fmaxf((float)(e - b), 1.0f);
  float4 o; o.x = s.x * inv; o.y = s.y * inv; o.z = s.z * inv; o.w = s.w * inv;
  *(float4*)(Mean + (size_t)chem * H + l32 * 4) = o;
}

// ---------------- fp32 projection (W_mol): xsb[chem] = bf16(Mean @ W + x_chem) ----------------

__global__ __launch_bounds__(256) void proj_kernel(
    const float* __restrict__ X, const float* __restrict__ W,
    const float* __restrict__ Res, u16* __restrict__ Yb, int N) {
  int r0 = blockIdx.x * 64;
  if (r0 >= N) return;
  __shared__ float Xs[64][132];
  int tid = threadIdx.x;
#pragma unroll
  for (int i = 0; i < 8; ++i) {
    int f = tid + 256 * i;
    int row = f >> 5, c4 = (f & 31) << 2;
    float4 v = make_float4(0.f, 0.f, 0.f, 0.f);
    if (r0 + row < N) v = *(const float4*)(X + (size_t)(r0 + row) * H + c4);
    *(float4*)&Xs[row][c4] = v;
  }
  __syncthreads();
  int trow = tid >> 5, tcol = tid & 31;
  float acc[8][4] = {};
#pragma unroll 4
  for (int k = 0; k < 128; ++k) {
    float4 w = *(const float4*)(W + k * H + tcol * 4);
#pragma unroll
    for (int i = 0; i < 8; ++i) {
      float xv = Xs[trow * 8 + i][k];
      acc[i][0] = fmaf(xv, w.x, acc[i][0]);
      acc[i][1] = fmaf(xv, w.y, acc[i][1]);
      acc[i][2] = fmaf(xv, w.z, acc[i][2]);
      acc[i][3] = fmaf(xv, w.w, acc[i][3]);
    }
  }
#pragma unroll
  for (int i = 0; i < 8; ++i) {
    int row = r0 + trow * 8 + i;
    if (row < N) {
      float4 rv = *(const float4*)(Res + (size_t)row * H + tcol * 4);
      u32 lo = (u32)f2bf(acc[i][0] + rv.x) | ((u32)f2bf(acc[i][1] + rv.y) << 16);
      u32 hi = (u32)f2bf(acc[i][2] + rv.z) | ((u32)f2bf(acc[i][3] + rv.w) << 16);
      *(uint2*)(Yb + (size_t)row * H + tcol * 4) = make_uint2(lo, hi);
    }
  }
}

// ---------------- converts ----------------

// xsb rows [20000,50000) = bf16([x_gene | x_assay])
__global__ __launch_bounds__(256) void conv_xs(const float* __restrict__ x_gene,
                                               const float* __restrict__ x_assay,
                                               u16* __restrict__ xsb) {
  int idx = 20000 * H + (blockIdx.x * 256 + threadIdx.x) * 4;
  if (idx >= 50000 * H) return;
  int row = idx >> 7;
  const float* src = (row < 40000) ? x_gene + (idx - 20000 * H) : x_assay + (idx - 40000 * H);
  float4 v = *(const float4*)src;
  u32 p0 = (u32)f2bf(v.x) | ((u32)f2bf(v.y) << 16);
  u32 p1 = (u32)f2bf(v.z) | ((u32)f2bf(v.w) << 16);
  u32* o = (u32*)(xsb + idx);
  o[0] = p0; o[1] = p1;
}

// WB[(mat*2+side)][n][k] = bf16( (side?Wr:Wl)[mat][k][n] )
__global__ __launch_bounds__(256) void conv_weights(const float* __restrict__ Wl,
                                                    const float* __restrict__ Wr,
                                                    u16* __restrict__ WB) {
  int mat = blockIdx.x;
  int side = blockIdx.y;
  const float* W = (side ? Wr : Wl) + (size_t)mat * H * H;
  u16* O = WB + ((size_t)mat * 2 + side) * H * H;
  for (int f = threadIdx.x; f < H * H; f += 256) {
    int n = f >> 7, k = f & 127;
    O[f] = f2bf(W[k * H + n]);
  }
}

// ---------------- batched bf16 MFMA projection: all 26 GEMMs of one layer ----------------

__global__ __launch_bounds__(256) void proj_mfma(
    const u16* __restrict__ xsb, const u16* __restrict__ WB,
    const float* __restrict__ bl, const float* __restrict__ br,
    u16* __restrict__ XLb, u16* __restrict__ XRb, int layer) {
  int by = blockIdx.y;
  int r = by >> 1, side = by & 1;
  int typ = side ? DST_T[r] : SRC_T[r];
  int N = NODE_N[typ];
  int r0 = blockIdx.x * 64;
  if (r0 >= N) return;
  const u16* X = xsb + (size_t)TYPE_OFF[typ] * H;
  const u16* W = WB + ((size_t)(layer * NREL + r) * 2 + side) * H * H;
  const float* bias = (side ? br : bl) + (size_t)(layer * NREL + r) * H;
  u16* Y = side ? (XRb + (size_t)XOFF_D[r] * H) : (XLb + (size_t)XOFF_S[r] * H);

  __shared__ u16 Xs[64 * 136];
  __shared__ u16 Ws[128 * 136];
  int tid = threadIdx.x;
#pragma unroll
  for (int i = 0; i < 4; ++i) {
    int f = tid + 256 * i;
    int row = f >> 4, seg = f & 15;
    ushort8 v = {};
    if (r0 + row < N) v = *(const ushort8*)(X + (size_t)(r0 + row) * H + seg * 8);
    *(ushort8*)(Xs + row * 136 + seg * 8) = v;
  }
#pragma unroll
  for (int i = 0; i < 8; ++i) {
    int f = tid + 256 * i;
    int row = f >> 4, seg = f & 15;
    *(ushort8*)(Ws + row * 136 + seg * 8) = *(const ushort8*)(W + row * H + seg * 8);
  }
  __syncthreads();

  int w = tid >> 6, lane = tid & 63;
  int g = lane >> 4, l16 = lane & 15;
  floatx4 acc[4][2] = {};
#pragma unroll
  for (int kt = 0; kt < 4; ++kt) {
    int k0 = kt * 32 + g * 8;
    short8 a[4], b[2];
#pragma unroll
    for (int rt = 0; rt < 4; ++rt) a[rt] = *(const short8*)(Xs + (rt * 16 + l16) * 136 + k0);
#pragma unroll
    for (int ct = 0; ct < 2; ++ct) b[ct] = *(const short8*)(Ws + (w * 32 + ct * 16 + l16) * 136 + k0);
#pragma unroll
    for (int rt = 0; rt < 4; ++rt)
#pragma unroll
      for (int ct = 0; ct < 2; ++ct)
        acc[rt][ct] = __builtin_amdgcn_mfma_f32_16x16x32_bf16(a[rt], b[ct], acc[rt][ct], 0, 0, 0);
  }
  __syncthreads();
  float bv0 = bias[w * 32 + l16];
  float bv1 = bias[w * 32 + 16 + l16];
#pragma unroll
  for (int rt = 0; rt < 4; ++rt)
#pragma unroll
    for (int ct = 0; ct < 2; ++ct) {
      float bv = ct ? bv1 : bv0;
      int col = w * 32 + ct * 16 + l16;
#pragma unroll
      for (int reg = 0; reg < 4; ++reg) {
        int row = rt * 16 + g * 4 + reg;
        Xs[row * 136 + col] = f2bf(acc[rt][ct][reg] + bv);
      }
    }
  __syncthreads();
#pragma unroll
  for (int i = 0; i < 4; ++i) {
    int f = tid + 256 * i;
    int row = f >> 4, seg = f & 15;
    if (r0 + row < N)
      *(ushort8*)(Y + (size_t)(r0 + row) * H + seg * 8) = *(const ushort8*)(Xs + row * 136 + seg * 8);
  }
}

// ---------------- fused GATv2: 4 dsts/wave, 16-lane groups, no-max softmax, pipelined gathers ----------------

__global__ __launch_bounds__(256, 8) void gat_fused(
    const u16* __restrict__ XLb, const u16* __restrict__ XRb,
    const int* __restrict__ rp, const u32* __restrict__ Ae,
    const float* __restrict__ att_a, const float* __restrict__ cbv,
    float* __restrict__ agg, int layer) {
  int wave = (blockIdx.x * blockDim.x + threadIdx.x) >> 6;
  int lane = threadIdx.x & 63;
  int g = lane >> 4, l16 = lane & 15;
  int d = wave * 4 + g;                    // grid sized so d in [0,50000) exactly
  int dt = d < 20000 ? 0 : (d < 40000 ? 1 : 2);
  int dl = d - TYPE_OFF[dt];
  float o[8] = {};
  int nr = NREL_OF[dt];
  for (int rr = 0; rr < nr; ++rr) {
    int r = RELS_OF[dt][rr];
    size_t wi = (size_t)layer * NREL + r;
    const u16* XL = XLb + ((size_t)XOFF_S[r] << 7);
    ushort8 uxr = *(const ushort8*)(XRb + ((size_t)(XOFF_D[r] + dl) << 7) + (l16 << 3));
    float4 a0 = *(const float4*)(att_a + wi * H + (l16 << 3));
    float4 a1 = *(const float4*)(att_a + wi * H + (l16 << 3) + 4);
    float av[8] = {a0.x, a0.y, a0.z, a0.w, a1.x, a1.y, a1.z, a1.w};
    float xr[8];
#pragma unroll
    for (int c = 0; c < 8; ++c) xr[c] = bf2f((u16)uxr[c]);
    const int* rpr = rp + SEG_RO[r + 1];
    const u32* pe = Ae + (size_t)r * EDG;
    int b = rpr[dl], e = rpr[dl + 1];
    float s = 0.f;
    float V[8] = {};

    // pair accumulate: no running max (scores bounded; plain exp is exact softmax)
    auto pair_acc = [&](const ushort8& u0, const ushort8& u1) {
      float xl0[8], xl1[8], t0 = 0.f, t1 = 0.f;
#pragma unroll
      for (int c = 0; c < 8; ++c) {
        xl0[c] = bf2f((u16)u0[c]);
        xl1[c] = bf2f((u16)u1[c]);
        float v0 = xl0[c] + xr[c], v1 = xl1[c] + xr[c];
        t0 = fmaf(av[c], fmaxf(v0, 0.2f * v0), t0);
        t1 = fmaf(av[c], fmaxf(v1, 0.2f * v1), t1);
      }
      t0 += __shfl_xor(t0, 1, 64); t1 += __shfl_xor(t1, 1, 64);
      t0 += __shfl_xor(t0, 2, 64); t1 += __shfl_xor(t1, 2, 64);
      t0 += __shfl_xor(t0, 4, 64); t1 += __shfl_xor(t1, 4, 64);
      t0 += __shfl_xor(t0, 8, 64); t1 += __shfl_xor(t1, 8, 64);
      float w0 = __expf(t0), w1 = __expf(t1);
      s += w0 + w1;
#pragma unroll
      for (int c = 0; c < 8; ++c)
        V[c] = fmaf(w1, xl1[c], fmaf(w0, xl0[c], V[c]));
    };

    int npair = (e - b) >> 1;
    int j = b;
    if (npair > 0) {
      // 2-deep index prefetch + 1-deep row prefetch. Over-reads of pe past e
      // stay inside Ae/Be workspace (values never used).
      u32 i0 = pe[j], i1 = pe[j + 1];
      u32 i2 = pe[j + 2], i3 = pe[j + 3];
      ushort8 u0 = *(const ushort8*)(XL + ((size_t)(i0 & 32767u) << 7) + (l16 << 3));
      ushort8 u1 = *(const ushort8*)(XL + ((size_t)(i1 & 32767u) << 7) + (l16 << 3));
      for (int it = 1; it < npair; ++it) {
        ushort8 n0 = *(const ushort8*)(XL + ((size_t)(i2 & 32767u) << 7) + (l16 << 3));
        ushort8 n1 = *(const ushort8*)(XL + ((size_t)(i3 & 32767u) << 7) + (l16 << 3));
        i2 = pe[j + 2 * it + 2];
        i3 = pe[j + 2 * it + 3];
        pair_acc(u0, u1);
        u0 = n0; u1 = n1;
      }
      pair_acc(u0, u1);
      j += 2 * npair;
    }
    if (j < e) {                           // odd tail edge
      u32 p0 = pe[j];
      ushort8 u0 = *(const ushort8*)(XL + ((size_t)(p0 & 32767u) << 7) + (l16 << 3));
      float xl0[8], t0 = 0.f;
#pragma unroll
      for (int c = 0; c < 8; ++c) {
        xl0[c] = bf2f((u16)u0[c]);
        float v0 = xl0[c] + xr[c];
        t0 = fmaf(av[c], fmaxf(v0, 0.2f * v0), t0);
      }
      t0 += __shfl_xor(t0, 1, 64);
      t0 += __shfl_xor(t0, 2, 64);
      t0 += __shfl_xor(t0, 4, 64);
      t0 += __shfl_xor(t0, 8, 64);
      float w0 = __expf(t0);
      s += w0;
#pragma unroll
      for (int c = 0; c < 8; ++c) V[c] = fmaf(w0, xl0[c], V[c]);
    }
    if (s > 0.f) {
      float inv = 1.0f / s;
#pragma unroll
      for (int c = 0; c < 8; ++c) o[c] = fmaf(V[c], inv, o[c]);
    }
    float4 c0 = *(const float4*)(cbv + wi * H + (l16 << 3));
    float4 c1 = *(const float4*)(cbv + wi * H + (l16 << 3) + 4);
    o[0] += c0.x; o[1] += c0.y; o[2] += c0.z; o[3] += c0.w;
    o[4] += c1.x; o[5] += c1.y; o[6] += c1.z; o[7] += c1.w;
  }
  float* ap = agg + ((size_t)d << 7) + (l16 << 3);
  *(float4*)ap       = make_float4(o[0], o[1], o[2], o[3]);
  *(float4*)(ap + 4) = make_float4(o[4], o[5], o[6], o[7]);
}

// ---------------- LayerNorm + ReLU (fp32 in, bf16 out) ----------------

__global__ __launch_bounds__(256) void ln_relu_kernel(const float* __restrict__ agg,
                                                      const float* __restrict__ g,
                                                      const float* __restrict__ b,
                                                      u16* __restrict__ xsb) {
  int row = (blockIdx.x * blockDim.x + threadIdx.x) >> 6;
  int lane = threadIdx.x & 63;
  if (row >= 50000) return;
  int t = row < 20000 ? 0 : (row < 40000 ? 1 : 2);
  float2 x = *(const float2*)(agg + (size_t)row * H + 2 * lane);
  float mu = wave_reduce_sum(x.x + x.y) * (1.f / 128.f);
  float d0 = x.x - mu, d1 = x.y - mu;
  float var = wave_reduce_sum(d0 * d0 + d1 * d1) * (1.f / 128.f);
  float inv = 1.0f / sqrtf(var + 1e-5f);
  float2 gg = *(const float2*)(g + t * H + 2 * lane);
  float2 bb = *(const float2*)(b + t * H + 2 * lane);
  float o0 = fmaxf(d0 * inv * gg.x + bb.x, 0.f);
  float o1 = fmaxf(d1 * inv * gg.y + bb.y, 0.f);
  u32 pk = (u32)f2bf(o0) | ((u32)f2bf(o1) << 16);
  *(u32*)(xsb + (size_t)row * H + 2 * lane) = pk;
}

// ---------------- prediction head ----------------

__global__ __launch_bounds__(256) void pred_kernel(const u16* __restrict__ xsb,
                                                   const float* __restrict__ Wp,
                                                   const float* __restrict__ bp,
                                                   float* __restrict__ out) {
  int row = (blockIdx.x * blockDim.x + threadIdx.x) >> 6;
  int lane = threadIdx.x & 63;
  if (row >= 20000) return;
  u32 u = *(const u32*)(xsb + (size_t)row * H + 2 * lane);
  float x0 = bflo(u), x1 = bfhi(u);
  float4 w = *(const float4*)(Wp + 4 * lane);
  float pA = x0 * w.x + x1 * w.z;
  float pB = x0 * w.y + x1 * w.w;
  pA = wave_reduce_sum(pA);
  pB = wave_reduce_sum(pB);
  if (lane == 0) {
    out[(size_t)row * 2 + 0] = pA + bp[0];
    out[(size_t)row * 2 + 1] = pB + bp[1];
  }
}

// ---------------- launch ----------------

extern "C" void kernel_launch(void* const* d_in, const int* in_sizes, int n_in,
                              void* d_out, int out_size, void* d_ws, size_t ws_size,
                              hipStream_t stream) {
  (void)in_sizes; (void)n_in; (void)out_size; (void)ws_size;
  const float* x_atom  = (const float*)d_in[0];
  const float* x_chem  = (const float*)d_in[1];
  const float* x_gene  = (const float*)d_in[2];
  const float* x_assay = (const float*)d_in[3];
  const float* W_mol   = (const float*)d_in[4];
  const float* Wl      = (const float*)d_in[5];
  const float* Wr      = (const float*)d_in[6];
  const float* bl      = (const float*)d_in[7];
  const float* br      = (const float*)d_in[8];
  const float* att_a   = (const float*)d_in[9];
  const float* cb      = (const float*)d_in[10];
  const float* ln_g    = (const float*)d_in[11];
  const float* ln_b    = (const float*)d_in[12];
  const float* Wp      = (const float*)d_in[13];
  const float* bp      = (const float*)d_in[14];
  const int*   hyper   = (const int*)d_in[15];
  const int*   ei      = (const int*)d_in[16];
  float* out = (float*)d_out;

  float* ws = (float*)d_ws;
  size_t o = 0;
  float* agg  = ws + o; o += (size_t)50000 * H;
  float* Mean = ws + o; o += (size_t)20000 * H;
  int2*  Aa   = (int2*)(ws + o); o += (size_t)2 * NATOM;
  int2*  Ba   = (int2*)(ws + o); o += (size_t)2 * NATOM;
  u32*   Ae   = (u32*)(ws + o); o += (size_t)NREL * EDG;
  u32*   Be   = (u32*)(ws + o); o += (size_t)NREL * EDG;
  int*   rp   = (int*)(ws + o); o += RP_TOTAL;
  int*   bh   = (int*)(ws + o); o += BH_TOTAL;
  u16*   xsb  = (u16*)(ws + o); o += (size_t)50000 * H / 2;
  u16*   WB   = (u16*)(ws + o); o += (size_t)52 * H * H / 2;
  u16*   XLb  = (u16*)(ws + o); o += (size_t)XTOT * H / 2;
  u16*   XRb  = (u16*)(ws + o); o += (size_t)XTOT * H / 2;

  dim3 b256(256);

  // ---- CSR build: atoms (int2) + edges (packed u32), 2-pass stable radix ----
  radix_init_a<<<dim3(2344), b256, 0, stream>>>(hyper, Aa);
  radix_init_e<<<dim3(1563, 13), b256, 0, stream>>>(ei, Ae);
  radix_count_t<int2><<<dim3(147, 1), b256, 0, stream>>>(Aa, bh, 0, 0);
  radix_count_t<u32><<<dim3(98, 13), b256, 0, stream>>>(Ae, bh, 15, 1);
  radix_scan<<<SEGS, b256, 0, stream>>>(bh);
  radix_scat_t<int2><<<dim3(147, 1), b256, 0, stream>>>(Aa, Ba, bh, 0, 0);
  radix_scat_t<u32><<<dim3(98, 13), b256, 0, stream>>>(Ae, Be, bh, 15, 1);
  radix_count_t<int2><<<dim3(147, 1), b256, 0, stream>>>(Ba, bh, 8, 0);
  radix_count_t<u32><<<dim3(98, 13), b256, 0, stream>>>(Be, bh, 23, 1);
  radix_scan<<<SEGS, b256, 0, stream>>>(bh);
  radix_scat_t<int2><<<dim3(147, 1), b256, 0, stream>>>(Ba, Aa, bh, 8, 0);
  radix_scat_t<u32><<<dim3(98, 13), b256, 0, stream>>>(Be, Ae, bh, 23, 1);
  build_rp_a<<<dim3(2344), b256, 0, stream>>>(Aa, rp);
  build_rp_e<<<dim3(1563, 13), b256, 0, stream>>>(Ae, rp);

  // ---- features: xsb[chem] = bf16(mean @ W_mol + x_chem); xsb[gene|assay] = bf16(raw) ----
  mean_atoms<<<dim3(20000 / 8), b256, 0, stream>>>(x_atom, rp, Aa, Mean);
  proj_kernel<<<dim3(313), b256, 0, stream>>>(Mean, W_mol, x_chem, xsb, 20000);
  conv_xs<<<dim3(3750), b256, 0, stream>>>(x_gene, x_assay, xsb);
  conv_weights<<<dim3(26, 2), b256, 0, stream>>>(Wl, Wr, WB);

  for (int l = 0; l < NLAYER; ++l) {
    proj_mfma<<<dim3(313, 26), b256, 0, stream>>>(xsb, WB, bl, br, XLb, XRb, l);
    gat_fused<<<dim3(3125), b256, 0, stream>>>(XLb, XRb, rp, Ae, att_a, cb, agg, l);
    ln_relu_kernel<<<dim3(50000 / 4), b256, 0, stream>>>(agg, ln_g + l * 3 * H, ln_b + l * 3 * H, xsb);
  }
  pred_kernel<<<dim3(20000 / 4), b256, 0, stream>>>(xsb, Wp, bp, out);
}